// Round 6
// baseline (250.039 us; speedup 1.0000x reference)
//
#include <hip/hip_runtime.h>
#include <stdint.h>
#include <math.h>

#define B_ 2
#define N_ 2048
#define D_ 1024
#define H_ 16
#define HD_ 64
#define TOK (B_*N_)        // 4096 tokens
#define INNER_ (H_*HD_)    // 1024

typedef unsigned short u16;
typedef __attribute__((ext_vector_type(8))) short bf16x8;
typedef __attribute__((ext_vector_type(4))) float f32x4;
typedef __attribute__((ext_vector_type(16))) float f32x16;

__device__ __forceinline__ float bf2f(u16 u) {
  union { uint32_t i; float f; } v; v.i = ((uint32_t)u) << 16; return v.f;
}
__device__ __forceinline__ u16 f2bf(float f) {
  union { uint32_t i; float f; } v; v.f = f;
  uint32_t r = ((v.i >> 16) & 1u) + 0x7fffu;   // round-to-nearest-even
  return (u16)((v.i + r) >> 16);
}
__device__ __forceinline__ uint32_t pk_trunc(float a, float b) {
  return __builtin_amdgcn_perm(__float_as_uint(b), __float_as_uint(a), 0x07060302);
}
__device__ __forceinline__ uint32_t pk_rnd(float a, float b) {
  uint32_t ua = __float_as_uint(a) + 0x8000u;
  uint32_t ub = __float_as_uint(b) + 0x8000u;
  return __builtin_amdgcn_perm(ub, ua, 0x07060302);
}
__device__ __forceinline__ void gl_lds16(const void* g, void* l) {
  __builtin_amdgcn_global_load_lds(
      (const __attribute__((address_space(1))) uint32_t*)g,
      (__attribute__((address_space(3))) uint32_t*)l, 16, 0, 0);
}
__device__ __forceinline__ f32x4 mfma16(bf16x8 a, bf16x8 b, f32x4 c) {
  return __builtin_amdgcn_mfma_f32_16x16x32_bf16(a, b, c, 0, 0, 0);
}
__device__ __forceinline__ f32x16 mfma32(bf16x8 a, bf16x8 b, f32x16 c) {
  return __builtin_amdgcn_mfma_f32_32x32x16_bf16(a, b, c, 0, 0, 0);
}

// -------- mask -> bitmask, transposed layout bitsT[b][j64][row(2048)] --------
__global__ void pack_mask(const int* __restrict__ mask, uint64_t* __restrict__ bits) {
  int t = threadIdx.x, lane = t & 63, w = t >> 6;
  int seg = blockIdx.x * 4 + w;
  int row = seg >> 3, s = seg & 7;
  const int* mp = mask + (size_t)row * 2048 + s * 256;
  int b = row >> 11, i = row & 2047;
  uint64_t* bp = bits + (size_t)b * 32 * 2048 + i;
  for (int j = 0; j < 4; j++) {
    int m = mp[j * 64 + lane];
    uint64_t bm = __ballot(m > 0);
    if (lane == 0) bp[(size_t)(s * 4 + j) * 2048] = bm;
  }
}

// -------- RoPE sin/cos table: rtab[pos][p] = {sin, cos} ----------------------
__global__ void rtab_kernel(float2* __restrict__ rtab) {
  int i = blockIdx.x * 256 + threadIdx.x;
  int pos = i >> 5, p = i & 31;
  float inv = exp2f(-(float)p * (13.287712379549449f / 32.0f));
  float sn, cs;
  sincosf((float)pos * inv, &sn, &cs);
  rtab[i] = make_float2(sn, cs);
}

// ------- fp32 -> bf16 transpose --------------------------------------------
__global__ void transpose_f2b(const float* __restrict__ in, u16* __restrict__ out,
                              int R, int C) {
  __shared__ u16 tile[64][65];
  int c0 = blockIdx.x * 64, r0 = blockIdx.y * 64;
  int t = threadIdx.x;
  int c = t & 63, r4 = t >> 6;
  for (int i = 0; i < 16; i++) {
    int r = r4 + i * 4;
    tile[c][r] = f2bf(in[(size_t)(r0 + r) * C + c0 + c]);
  }
  __syncthreads();
  int rr = t & 63, cc4 = t >> 6;
  for (int i = 0; i < 16; i++) {
    int cc = cc4 + i * 4;
    out[(size_t)(c0 + cc) * R + r0 + rr] = tile[cc][rr];
  }
}

// ---------------- LayerNorm -------------------------------------------------
__global__ void ln_kernel(const float* __restrict__ x, const float* __restrict__ gamma,
                          const float* __restrict__ beta, u16* __restrict__ xn) {
  int row = blockIdx.x, t = threadIdx.x;
  const float* xr = x + (size_t)row * D_;
  float4 u = *(const float4*)(xr + t * 4);
  float s = u.x + u.y + u.z + u.w;
  float ss = u.x * u.x + u.y * u.y + u.z * u.z + u.w * u.w;
  for (int off = 1; off < 64; off <<= 1) {
    s += __shfl_xor(s, off);
    ss += __shfl_xor(ss, off);
  }
  __shared__ float red[8];
  int wid = t >> 6, lane = t & 63;
  if (lane == 0) { red[wid] = s; red[wid + 4] = ss; }
  __syncthreads();
  s = red[0] + red[1] + red[2] + red[3];
  ss = red[4] + red[5] + red[6] + red[7];
  float mu = s * (1.0f / D_);
  float var = ss * (1.0f / D_) - mu * mu;
  float rinv = rsqrtf(var + 1e-5f);
  float4 g4 = *(const float4*)(gamma + t * 4);
  float4 b4 = *(const float4*)(beta + t * 4);
  ushort4 o;
  o.x = f2bf((u.x - mu) * rinv * g4.x + b4.x);
  o.y = f2bf((u.y - mu) * rinv * g4.y + b4.y);
  o.z = f2bf((u.z - mu) * rinv * g4.z + b4.z);
  o.w = f2bf((u.w - mu) * rinv * g4.w + b4.w);
  *(ushort4*)(xn + (size_t)row * D_ + t * 4) = o;
}

// ------- QKV GEMM with fused RoPE/head-reorder/V-permute epilogue -----------
// V slot permutation = token-j with bits 2<->3 swapped (matches attn PV B-frag)
__global__ void gemm_qkv(const u16* __restrict__ A, const u16* __restrict__ Bt,
                         const float2* __restrict__ rtab,
                         u16* __restrict__ q, u16* __restrict__ k,
                         u16* __restrict__ vt) {
  const int K = 1024;
  __shared__ __align__(16) u16 As[128 * 64];
  __shared__ __align__(16) u16 Bs[128 * 64];
  const int t = threadIdx.x;
  const int lane = t & 63, wid = t >> 6;
  const int m0 = blockIdx.y * 128, n0 = blockIdx.x * 128;
  const int wm = (wid >> 1) * 64, wn = (wid & 1) * 64;
  const int l15 = lane & 15, quad = lane >> 4;

  f32x4 acc[4][4];
  const f32x4 zf = {0.f, 0.f, 0.f, 0.f};
  for (int i = 0; i < 4; i++) for (int j = 0; j < 4; j++) acc[i][j] = zf;

  for (int kb = 0; kb < K; kb += 64) {
    for (int i = 0; i < 4; i++) {
      int e = i * 256 + t;
      int row = e >> 3, gs = e & 7;
      int g = gs ^ (row & 7);
      gl_lds16(A + (size_t)(m0 + row) * K + kb + g * 8, &As[e * 8]);
      gl_lds16(Bt + (size_t)(n0 + row) * K + kb + g * 8, &Bs[e * 8]);
    }
    __syncthreads();
    bf16x8 af[4][2], bfr[4][2];
    for (int mt = 0; mt < 4; mt++)
      for (int kc = 0; kc < 2; kc++) {
        int row = wm + mt * 16 + l15;
        int gs = (kc * 4 + quad) ^ (row & 7);
        af[mt][kc] = *(const bf16x8*)&As[row * 64 + gs * 8];
      }
    for (int nt = 0; nt < 4; nt++)
      for (int kc = 0; kc < 2; kc++) {
        int row = wn + nt * 16 + l15;
        int gs = (kc * 4 + quad) ^ (row & 7);
        bfr[nt][kc] = *(const bf16x8*)&Bs[row * 64 + gs * 8];
      }
    for (int mt = 0; mt < 4; mt++)
      for (int nt = 0; nt < 4; nt++)
        for (int kc = 0; kc < 2; kc++)
          acc[mt][nt] = mfma16(af[mt][kc], bfr[nt][kc], acc[mt][nt]);
    __syncthreads();
  }

  const int sec = n0 >> 10;                       // 0=q 1=k 2=v
  const int h = ((n0 & 1023) >> 6) + (wn >> 6);
  if (sec < 2) {
    u16* dst = sec ? k : q;
    const float scale = sec ? 1.0f : 0.125f * 1.4426950408889634f;
    for (int mt = 0; mt < 4; mt++)
      for (int r = 0; r < 4; r++) {
        int row = m0 + wm + mt * 16 + quad * 4 + r;
        int b = row >> 11, pos = row & 2047;
        float2 c0 = rtab[pos * 32 + l15];
        float2 c1 = rtab[pos * 32 + 16 + l15];
        float a0 = acc[mt][0][r], a1 = acc[mt][1][r];
        float a2 = acc[mt][2][r], a3 = acc[mt][3][r];
        float o0 = (a0 * c0.y - a2 * c0.x) * scale;
        float o2 = (a2 * c0.y + a0 * c0.x) * scale;
        float o1 = (a1 * c1.y - a3 * c1.x) * scale;
        float o3 = (a3 * c1.y + a1 * c1.x) * scale;
        size_t base = ((size_t)(b * 16 + h) * 2048 + pos) * 64;
        dst[base + l15]      = f2bf(o0);
        dst[base + 16 + l15] = f2bf(o1);
        dst[base + 32 + l15] = f2bf(o2);
        dst[base + 48 + l15] = f2bf(o3);
      }
  } else {
    // vt[bh][d][n]: within each 64-token block, slot = j with bits2<->3 swapped
    for (int mt = 0; mt < 4; mt++) {
      int tb = m0 + wm + mt * 16;          // token base (multiple of 16)
      int bb = tb >> 11, nb = tb & 2047;
      int slot = nb + (quad & 1) * 8 + (quad >> 1) * 4;   // + r contiguous
      for (int nt = 0; nt < 4; nt++) {
        int d = nt * 16 + l15;
        size_t base = ((size_t)(bb * 16 + h) * 64 + d) * 2048 + slot;
        uint2 o;
        o.x = pk_rnd(acc[mt][nt][0], acc[mt][nt][1]);
        o.y = pk_rnd(acc[mt][nt][2], acc[mt][nt][3]);
        *(uint2*)&vt[base] = o;
      }
    }
  }
}

// ------- out-proj GEMM, 64x128 tile, double-buffered (2 blocks/CU) ----------
__global__ void gemm_out(const u16* __restrict__ A, const u16* __restrict__ Bt,
                         float* __restrict__ C, const float* __restrict__ bias) {
  const int N = 1024, K = 1024;
  __shared__ __align__(16) u16 As[2][64 * 64];
  __shared__ __align__(16) u16 Bs[2][128 * 64];
  const int t = threadIdx.x;
  const int lane = t & 63, wid = t >> 6;
  const int m0 = blockIdx.y * 64, n0 = blockIdx.x * 128;
  const int wm = (wid >> 1) * 32, wn = (wid & 1) * 64;
  const int l15 = lane & 15, quad = lane >> 4;

  f32x4 acc[2][4];
  const f32x4 zf = {0.f, 0.f, 0.f, 0.f};
  for (int i = 0; i < 2; i++) for (int j = 0; j < 4; j++) acc[i][j] = zf;

  {
    for (int i = 0; i < 2; i++) {
      int e = i * 256 + t;
      int row = e >> 3, gs = e & 7, g = gs ^ (row & 7);
      gl_lds16(A + (size_t)(m0 + row) * K + g * 8, &As[0][e * 8]);
    }
    for (int i = 0; i < 4; i++) {
      int e = i * 256 + t;
      int row = e >> 3, gs = e & 7, g = gs ^ (row & 7);
      gl_lds16(Bt + (size_t)(n0 + row) * K + g * 8, &Bs[0][e * 8]);
    }
  }
  for (int ki = 0; ki < 16; ki++) {
    int cur = ki & 1;
    __syncthreads();
    if (ki + 1 < 16) {
      int nxt = cur ^ 1, kb = (ki + 1) * 64;
      for (int i = 0; i < 2; i++) {
        int e = i * 256 + t;
        int row = e >> 3, gs = e & 7, g = gs ^ (row & 7);
        gl_lds16(A + (size_t)(m0 + row) * K + kb + g * 8, &As[nxt][e * 8]);
      }
      for (int i = 0; i < 4; i++) {
        int e = i * 256 + t;
        int row = e >> 3, gs = e & 7, g = gs ^ (row & 7);
        gl_lds16(Bt + (size_t)(n0 + row) * K + kb + g * 8, &Bs[nxt][e * 8]);
      }
    }
    bf16x8 af[2][2], bfr[4][2];
    for (int mt = 0; mt < 2; mt++)
      for (int kc = 0; kc < 2; kc++) {
        int row = wm + mt * 16 + l15;
        int gs = (kc * 4 + quad) ^ (row & 7);
        af[mt][kc] = *(const bf16x8*)&As[cur][row * 64 + gs * 8];
      }
    for (int nt = 0; nt < 4; nt++)
      for (int kc = 0; kc < 2; kc++) {
        int row = wn + nt * 16 + l15;
        int gs = (kc * 4 + quad) ^ (row & 7);
        bfr[nt][kc] = *(const bf16x8*)&Bs[cur][row * 64 + gs * 8];
      }
    for (int mt = 0; mt < 2; mt++)
      for (int nt = 0; nt < 4; nt++)
        for (int kc = 0; kc < 2; kc++)
          acc[mt][nt] = mfma16(af[mt][kc], bfr[nt][kc], acc[mt][nt]);
  }
  for (int mt = 0; mt < 2; mt++)
    for (int nt = 0; nt < 4; nt++)
      for (int r = 0; r < 4; r++) {
        int row = m0 + wm + mt * 16 + quad * 4 + r;
        int col = n0 + wn + nt * 16 + l15;
        C[(size_t)row * N + col] = acc[mt][nt][r] + bias[col];
      }
}

// ---------------- flash attention: 32x32x16 MFMA, S^T formulation -----------
// Block = 128 q-rows, 4 waves x 32 q-rows. S^T = K.Q^T: lane col=q=lane&31,
// rows j=(reg&3)+8*(reg>>2)+4*hi (+32*jt). Fixed-base softmax (scores bounded).
// P in-register feeds O^T = V^T.P: V slot permutation (j bits2<->3) makes the
// C-layout regs exactly the B-fragment; V^T A-frags are single b128 reads.
__global__ void attn_kernel(const u16* __restrict__ q, const u16* __restrict__ k,
                            const u16* __restrict__ vt, const uint64_t* __restrict__ bitsT,
                            u16* __restrict__ out) {
  int blk = blockIdx.x;
  int qt = blk & 15;
  int bh = blk >> 4;
  int b = bh >> 4, h = bh & 15;
  int q0 = qt * 128;
  int t = threadIdx.x, lane = t & 63, w = t >> 6;
  int l31 = lane & 31, hi = lane >> 5;

  __shared__ __align__(16) u16 sQ[128 * 64];
  __shared__ __align__(16) u16 sK[2][64 * 64];
  __shared__ __align__(16) u16 sV[2][64 * 64];

  // stage Q (4 iters) + K/V tile 0 (2 iters each)
  for (int i = 0; i < 4; i++) {
    int e = i * 256 + t;
    int row = e >> 3, g = (e & 7) ^ (row & 7);
    gl_lds16(q + ((size_t)bh * 2048 + q0 + row) * 64 + g * 8, &sQ[e * 8]);
  }
  for (int i = 0; i < 2; i++) {
    int e = i * 256 + t;
    int row = e >> 3, g = (e & 7) ^ (row & 7);
    gl_lds16(k + ((size_t)bh * 2048 + row) * 64 + g * 8, &sK[0][e * 8]);
    gl_lds16(vt + ((size_t)bh * 64 + row) * 2048 + g * 8, &sV[0][e * 8]);
  }
  __syncthreads();

  // Q as B-fragment: n=q-row=w*32+l31, k = kc*16 + 8*hi + e
  const int qrow_l = w * 32 + l31;
  bf16x8 bq[4];
  for (int kc = 0; kc < 4; kc++) {
    int gs = (kc * 2 + hi) ^ (qrow_l & 7);
    bq[kc] = *(const bf16x8*)&sQ[qrow_l * 64 + gs * 8];
  }

  float l_i = 0.f;
  f32x16 occ[2];
  for (int dt = 0; dt < 2; dt++)
    for (int i = 0; i < 16; i++) occ[dt][i] = 0.f;
  const int qrow = q0 + qrow_l;

  for (int j64 = 0; j64 < 32; j64++) {
    if (j64) __syncthreads();
    int cur = j64 & 1;
    if (j64 + 1 < 32) {
      int nxt = cur ^ 1, j0n = (j64 + 1) * 64;
      for (int i = 0; i < 2; i++) {
        int e = i * 256 + t;
        int row = e >> 3, g = (e & 7) ^ (row & 7);
        gl_lds16(k + ((size_t)bh * 2048 + j0n + row) * 64 + g * 8, &sK[nxt][e * 8]);
        gl_lds16(vt + ((size_t)bh * 64 + row) * 2048 + j0n + g * 8, &sV[nxt][e * 8]);
      }
    }
    const u16* sKc = sK[cur];
    const u16* sVc = sV[cur];

    uint64_t word = bitsT[((size_t)(b * 32 + j64)) * 2048 + qrow];

    float p[32];
    #pragma unroll
    for (int jt = 0; jt < 2; jt++) {
      f32x16 st;
      for (int i = 0; i < 16; i++) st[i] = 0.f;
      for (int kc = 0; kc < 4; kc++) {
        int row = jt * 32 + l31;
        int gs = (kc * 2 + hi) ^ (row & 7);
        bf16x8 ak = *(const bf16x8*)&sKc[row * 64 + gs * 8];
        st = mfma32(ak, bq[kc], st);
      }
      uint32_t mw = (uint32_t)(word >> (jt * 32)) >> (4 * hi);
      #pragma unroll
      for (int reg = 0; reg < 16; reg++) {
        int bitpos = (reg & 3) + 8 * (reg >> 2);
        bool on = (mw >> bitpos) & 1u;
        p[jt * 16 + reg] = on ? exp2f(st[reg]) : 0.f;
      }
    }
    float rsum = 0.f;
    for (int i = 0; i < 32; i++) rsum += p[i];
    rsum += __shfl_xor(rsum, 32);
    l_i += rsum;

    // O^T += V^T . P  (4 chunks of k=16; chunk c = regs [8*(c&1)..+7] of jt=c>>1)
    #pragma unroll
    for (int c = 0; c < 4; c++) {
      const float* pc = &p[(c >> 1) * 16 + (c & 1) * 8];
      union { bf16x8 v; uint32_t d[4]; } bp;
      bp.d[0] = pk_trunc(pc[0], pc[1]);
      bp.d[1] = pk_trunc(pc[2], pc[3]);
      bp.d[2] = pk_trunc(pc[4], pc[5]);
      bp.d[3] = pk_trunc(pc[6], pc[7]);
      for (int dt = 0; dt < 2; dt++) {
        int drow = dt * 32 + l31;
        int gs = (c * 2 + hi) ^ (drow & 7);
        bf16x8 av = *(const bf16x8*)&sVc[drow * 64 + gs * 8];
        occ[dt] = mfma32(av, bp.v, occ[dt]);
      }
    }
  }
  // epilogue: lane holds q-row=qrow, d = (reg&3)+8*(reg>>2)+4*hi+32*dt
  float rl = (l_i > 0.f) ? 1.0f / l_i : 0.f;
  size_t obase = ((size_t)b * 2048 + qrow) * 1024 + h * 64;
  for (int dt = 0; dt < 2; dt++)
    #pragma unroll
    for (int g = 0; g < 4; g++) {
      int d0 = dt * 32 + g * 8 + hi * 4;
      uint2 ov;
      ov.x = pk_rnd(occ[dt][g * 4 + 0] * rl, occ[dt][g * 4 + 1] * rl);
      ov.y = pk_rnd(occ[dt][g * 4 + 2] * rl, occ[dt][g * 4 + 3] * rl);
      *(uint2*)&out[obase + d0] = ov;
    }
}

extern "C" void kernel_launch(void* const* d_in, const int* in_sizes, int n_in,
                              void* d_out, int out_size, void* d_ws, size_t ws_size,
                              hipStream_t stream) {
  const float* x = (const float*)d_in[0];
  const int* mask = (const int*)d_in[1];
  const float* gamma = (const float*)d_in[2];
  const float* beta = (const float*)d_in[3];
  const float* wqkv = (const float*)d_in[4];
  const float* wout = (const float*)d_in[5];
  const float* bout = (const float*)d_in[6];
  float* out = (float*)d_out;

  uint8_t* ws = (uint8_t*)d_ws;
  size_t o = 0;
  uint64_t* mbits = (uint64_t*)(ws + o); o += (size_t)TOK * 32 * 8;
  u16* wqkvT = (u16*)(ws + o); o += (size_t)3 * INNER_ * D_ * 2;
  u16* woutT = (u16*)(ws + o); o += (size_t)INNER_ * D_ * 2;
  u16* xn    = (u16*)(ws + o); o += (size_t)TOK * D_ * 2;
  u16* qb    = (u16*)(ws + o); o += (size_t)TOK * INNER_ * 2;
  u16* kb    = (u16*)(ws + o); o += (size_t)TOK * INNER_ * 2;
  u16* vtb   = (u16*)(ws + o); o += (size_t)TOK * INNER_ * 2;
  u16* ao    = (u16*)(ws + o); o += (size_t)TOK * INNER_ * 2;
  float2* rtab = (float2*)(ws + o); o += (size_t)2048 * 32 * 8;

  pack_mask<<<8192, 256, 0, stream>>>(mask, mbits);
  rtab_kernel<<<256, 256, 0, stream>>>(rtab);
  transpose_f2b<<<dim3(3 * INNER_ / 64, D_ / 64), 256, 0, stream>>>(wqkv, wqkvT, D_, 3 * INNER_);
  transpose_f2b<<<dim3(D_ / 64, INNER_ / 64), 256, 0, stream>>>(wout, woutT, INNER_, D_);
  ln_kernel<<<TOK, 256, 0, stream>>>(x, gamma, beta, xn);
  gemm_qkv<<<dim3(3 * INNER_ / 128, TOK / 128), 256, 0, stream>>>(xn, wqkvT, rtab, qb, kb, vtb);
  attn_kernel<<<B_ * H_ * (N_ / 128), 256, 0, stream>>>(qb, kb, vtb, mbits, ao);
  gemm_out<<<dim3(D_ / 128, TOK / 64), 256, 0, stream>>>(ao, woutT, out, bout);
}

// Round 7
// 229.819 us; speedup vs baseline: 1.0880x; 1.0880x over previous
//
#include <hip/hip_runtime.h>
#include <stdint.h>
#include <math.h>

#define B_ 2
#define N_ 2048
#define D_ 1024
#define H_ 16
#define HD_ 64
#define TOK (B_*N_)        // 4096 tokens
#define INNER_ (H_*HD_)    // 1024

typedef unsigned short u16;
typedef __attribute__((ext_vector_type(8))) short bf16x8;
typedef __attribute__((ext_vector_type(4))) float f32x4;

__device__ __forceinline__ float bf2f(u16 u) {
  union { uint32_t i; float f; } v; v.i = ((uint32_t)u) << 16; return v.f;
}
__device__ __forceinline__ u16 f2bf(float f) {
  union { uint32_t i; float f; } v; v.f = f;
  uint32_t r = ((v.i >> 16) & 1u) + 0x7fffu;   // round-to-nearest-even
  return (u16)((v.i + r) >> 16);
}
__device__ __forceinline__ uint32_t pk_trunc(float a, float b) {
  return __builtin_amdgcn_perm(__float_as_uint(b), __float_as_uint(a), 0x07060302);
}
__device__ __forceinline__ uint32_t pk_rnd(float a, float b) {
  uint32_t ua = __float_as_uint(a) + 0x8000u;
  uint32_t ub = __float_as_uint(b) + 0x8000u;
  return __builtin_amdgcn_perm(ub, ua, 0x07060302);
}
__device__ __forceinline__ void gl_lds16(const void* g, void* l) {
  __builtin_amdgcn_global_load_lds(
      (const __attribute__((address_space(1))) uint32_t*)g,
      (__attribute__((address_space(3))) uint32_t*)l, 16, 0, 0);
}
__device__ __forceinline__ f32x4 mfma16(bf16x8 a, bf16x8 b, f32x4 c) {
  return __builtin_amdgcn_mfma_f32_16x16x32_bf16(a, b, c, 0, 0, 0);
}

// ---------------- fused prologue: ln / transposes / pack_mask / rtab --------
// block ranges: [0,4096) ln | [4096,4864) T(wqkv) | [4864,5120) T(wout)
//               | [5120,13312) pack_mask | [13312,13568) rtab
__global__ void prep_kernel(const float* __restrict__ x, const float* __restrict__ gamma,
                            const float* __restrict__ beta, u16* __restrict__ xn,
                            const float* __restrict__ wqkv, u16* __restrict__ wqkvT,
                            const float* __restrict__ wout, u16* __restrict__ woutT,
                            const int* __restrict__ mask, uint64_t* __restrict__ bits,
                            float2* __restrict__ rtab) {
  __shared__ u16 tile[64][65];
  __shared__ float red[8];
  int blk = blockIdx.x, t = threadIdx.x;
  if (blk < 4096) {                       // ----- LayerNorm row -----
    int row = blk;
    const float* xr = x + (size_t)row * D_;
    float4 u = *(const float4*)(xr + t * 4);
    float s = u.x + u.y + u.z + u.w;
    float ss = u.x * u.x + u.y * u.y + u.z * u.z + u.w * u.w;
    for (int off = 1; off < 64; off <<= 1) {
      s += __shfl_xor(s, off);
      ss += __shfl_xor(ss, off);
    }
    int wid = t >> 6, lane = t & 63;
    if (lane == 0) { red[wid] = s; red[wid + 4] = ss; }
    __syncthreads();
    s = red[0] + red[1] + red[2] + red[3];
    ss = red[4] + red[5] + red[6] + red[7];
    float mu = s * (1.0f / D_);
    float var = ss * (1.0f / D_) - mu * mu;
    float rinv = rsqrtf(var + 1e-5f);
    float4 g4 = *(const float4*)(gamma + t * 4);
    float4 b4 = *(const float4*)(beta + t * 4);
    ushort4 o;
    o.x = f2bf((u.x - mu) * rinv * g4.x + b4.x);
    o.y = f2bf((u.y - mu) * rinv * g4.y + b4.y);
    o.z = f2bf((u.z - mu) * rinv * g4.z + b4.z);
    o.w = f2bf((u.w - mu) * rinv * g4.w + b4.w);
    *(ushort4*)(xn + (size_t)row * D_ + t * 4) = o;
  } else if (blk < 5120) {                // ----- weight transpose fp32->bf16 -----
    const float* in; u16* outp; int R, C, bx, by;
    if (blk < 4864) { int idx = blk - 4096; in = wqkv; outp = wqkvT; R = 1024; C = 3072; bx = idx % 48; by = idx / 48; }
    else            { int idx = blk - 4864; in = wout; outp = woutT; R = 1024; C = 1024; bx = idx % 16; by = idx / 16; }
    int c0 = bx * 64, r0 = by * 64;
    int c = t & 63, r4 = t >> 6;
    for (int i = 0; i < 16; i++) {
      int r = r4 + i * 4;
      tile[c][r] = f2bf(in[(size_t)(r0 + r) * C + c0 + c]);
    }
    __syncthreads();
    int rr = t & 63, cc4 = t >> 6;
    for (int i = 0; i < 16; i++) {
      int cc = cc4 + i * 4;
      outp[(size_t)(c0 + cc) * R + r0 + rr] = tile[cc][rr];
    }
  } else if (blk < 13312) {               // ----- mask -> bitsT[b][j64][row] -----
    int idx = blk - 5120;
    int lane = t & 63, w = t >> 6;
    int seg = idx * 4 + w;
    int row = seg >> 3, s = seg & 7;
    const int* mp = mask + (size_t)row * 2048 + s * 256;
    int b = row >> 11, i = row & 2047;
    uint64_t* bp = bits + (size_t)b * 32 * 2048 + i;
    for (int j = 0; j < 4; j++) {
      int m = mp[j * 64 + lane];
      uint64_t bm = __ballot(m > 0);
      if (lane == 0) bp[(size_t)(s * 4 + j) * 2048] = bm;
    }
  } else {                                 // ----- RoPE sin/cos table -----
    int i = (blk - 13312) * 256 + t;
    int pos = i >> 5, p = i & 31;
    float inv = exp2f(-(float)p * (13.287712379549449f / 32.0f));
    float sn, cs;
    sincosf((float)pos * inv, &sn, &cs);
    rtab[i] = make_float2(sn, cs);
  }
}

// ------- QKV GEMM + fused RoPE/head-reorder epilogue -----------------------
// q/k written PRE-SWIZZLED in attn's LDS image order, per (bh, 64-token tile):
//   image[e*8 + o] = value(row = e>>3, dim = ((e&7)^(row&7))*8 + o)
// -> attn staging is a flat contiguous 4096-u16 copy.  V written row-major
// [bh][d][2048] with within-64 slot perm: j=32c+16hi+4q+r -> 32c+8q+4hi+r.
__global__ void gemm_qkv(const u16* __restrict__ A, const u16* __restrict__ Bt,
                         const float2* __restrict__ rtab,
                         u16* __restrict__ q, u16* __restrict__ k,
                         u16* __restrict__ vt) {
  const int K = 1024;
  __shared__ __align__(16) u16 smem[16384];   // As=smem[0:8192], Bs=smem[8192:]
  u16* As = smem;
  u16* Bs = smem + 8192;
  const int t = threadIdx.x;
  const int lane = t & 63, wid = t >> 6;
  const int m0 = blockIdx.y * 128, n0 = blockIdx.x * 128;
  const int wm = (wid >> 1) * 64, wn = (wid & 1) * 64;
  const int l15 = lane & 15, quad = lane >> 4;

  f32x4 acc[4][4];
  const f32x4 zf = {0.f, 0.f, 0.f, 0.f};
  for (int i = 0; i < 4; i++) for (int j = 0; j < 4; j++) acc[i][j] = zf;

  for (int kb = 0; kb < K; kb += 64) {
    for (int i = 0; i < 4; i++) {
      int e = i * 256 + t;
      int row = e >> 3, gs = e & 7;
      int g = gs ^ (row & 7);
      gl_lds16(A + (size_t)(m0 + row) * K + kb + g * 8, &As[e * 8]);
      gl_lds16(Bt + (size_t)(n0 + row) * K + kb + g * 8, &Bs[e * 8]);
    }
    __syncthreads();
    bf16x8 af[4][2], bfr[4][2];
    for (int mt = 0; mt < 4; mt++)
      for (int kc = 0; kc < 2; kc++) {
        int row = wm + mt * 16 + l15;
        int gs = (kc * 4 + quad) ^ (row & 7);
        af[mt][kc] = *(const bf16x8*)&As[row * 64 + gs * 8];
      }
    for (int nt = 0; nt < 4; nt++)
      for (int kc = 0; kc < 2; kc++) {
        int row = wn + nt * 16 + l15;
        int gs = (kc * 4 + quad) ^ (row & 7);
        bfr[nt][kc] = *(const bf16x8*)&Bs[row * 64 + gs * 8];
      }
    for (int mt = 0; mt < 4; mt++)
      for (int nt = 0; nt < 4; nt++)
        for (int kc = 0; kc < 2; kc++)
          acc[mt][nt] = mfma16(af[mt][kc], bfr[nt][kc], acc[mt][nt]);
    __syncthreads();
  }

  const int sec = n0 >> 10;                       // 0=q 1=k 2=v
  const int h_base = (n0 & 1023) >> 6;
  if (sec < 2) {
    // RoPE into LDS images (wave-private 4096-u16 region), then coalesced out
    u16* dst = sec ? k : q;
    const float scale = sec ? 1.0f : 0.125f * 1.4426950408889634f;
    const int img = (wn >> 6) * 2 + (wm >> 6);     // wave-uniform
    u16* im = smem + img * 4096;
    for (int mt = 0; mt < 4; mt++)
      for (int r = 0; r < 4; r++) {
        int lr = mt * 16 + quad * 4 + r;           // local row 0..63
        int rowg = m0 + wm + lr;
        int pos = rowg & 2047;
        float2 c0 = rtab[pos * 32 + l15];
        float2 c1 = rtab[pos * 32 + 16 + l15];
        float a0 = acc[mt][0][r], a1 = acc[mt][1][r];
        float a2 = acc[mt][2][r], a3 = acc[mt][3][r];
        float o0 = (a0 * c0.y - a2 * c0.x) * scale;   // d = l15
        float o1 = (a1 * c1.y - a3 * c1.x) * scale;   // d = l15+16
        float o2 = (a2 * c0.y + a0 * c0.x) * scale;   // d = l15+32
        float o3 = (a3 * c1.y + a1 * c1.x) * scale;   // d = l15+48
        int rx = lr & 7, dl = l15 & 7, dh = l15 >> 3;
        int base = lr * 64;
        im[base + ((0 + dh) ^ rx) * 8 + dl] = f2bf(o0);
        im[base + ((2 + dh) ^ rx) * 8 + dl] = f2bf(o1);
        im[base + ((4 + dh) ^ rx) * 8 + dl] = f2bf(o2);
        im[base + ((6 + dh) ^ rx) * 8 + dl] = f2bf(o3);
      }
    __syncthreads();
    for (int i = 0; i < 8; i++) {
      int u = i * 2048 + t * 8;
      int ig = u >> 12, off = u & 4095;
      int hh = ig >> 1, tt = ig & 1;
      int rowg0 = m0 + tt * 64;
      int bb = rowg0 >> 11;
      int tl = (rowg0 & 2047) >> 6;
      size_t base = ((size_t)(bb * 16 + h_base + hh) * 32 + tl) * 4096 + off;
      *(uint4*)&dst[base] = *(const uint4*)&smem[u];
    }
  } else {
    // vt[bh][d][2048], slot perm within each 64-token block
    const int h = h_base + (wn >> 6);
    for (int mt = 0; mt < 4; mt++) {
      int tb = wm + mt * 16;
      int bb = (m0 + tb) >> 11;
      int n64 = ((m0 + tb) & 2047) & ~63;
      int slot = n64 + (tb & 32) + ((tb & 16) >> 2) + quad * 8;
      for (int nt = 0; nt < 4; nt++) {
        int d = nt * 16 + l15;
        size_t base = ((size_t)(bb * 16 + h) * 64 + d) * 2048 + slot;
        uint2 o;
        o.x = pk_rnd(acc[mt][nt][0], acc[mt][nt][1]);
        o.y = pk_rnd(acc[mt][nt][2], acc[mt][nt][3]);
        *(uint2*)&vt[base] = o;
      }
    }
  }
}

// ------- out-proj GEMM, 64x128 tile, double-buffered -----------------------
__global__ void gemm_out(const u16* __restrict__ A, const u16* __restrict__ Bt,
                         float* __restrict__ C, const float* __restrict__ bias) {
  const int N = 1024, K = 1024;
  __shared__ __align__(16) u16 As[2][64 * 64];
  __shared__ __align__(16) u16 Bs[2][128 * 64];
  const int t = threadIdx.x;
  const int lane = t & 63, wid = t >> 6;
  const int m0 = blockIdx.y * 64, n0 = blockIdx.x * 128;
  const int wm = (wid >> 1) * 32, wn = (wid & 1) * 64;
  const int l15 = lane & 15, quad = lane >> 4;

  f32x4 acc[2][4];
  const f32x4 zf = {0.f, 0.f, 0.f, 0.f};
  for (int i = 0; i < 2; i++) for (int j = 0; j < 4; j++) acc[i][j] = zf;

  {
    for (int i = 0; i < 2; i++) {
      int e = i * 256 + t;
      int row = e >> 3, gs = e & 7, g = gs ^ (row & 7);
      gl_lds16(A + (size_t)(m0 + row) * K + g * 8, &As[0][e * 8]);
    }
    for (int i = 0; i < 4; i++) {
      int e = i * 256 + t;
      int row = e >> 3, gs = e & 7, g = gs ^ (row & 7);
      gl_lds16(Bt + (size_t)(n0 + row) * K + g * 8, &Bs[0][e * 8]);
    }
  }
  for (int ki = 0; ki < 16; ki++) {
    int cur = ki & 1;
    __syncthreads();
    if (ki + 1 < 16) {
      int nxt = cur ^ 1, kb = (ki + 1) * 64;
      for (int i = 0; i < 2; i++) {
        int e = i * 256 + t;
        int row = e >> 3, gs = e & 7, g = gs ^ (row & 7);
        gl_lds16(A + (size_t)(m0 + row) * K + kb + g * 8, &As[nxt][e * 8]);
      }
      for (int i = 0; i < 4; i++) {
        int e = i * 256 + t;
        int row = e >> 3, gs = e & 7, g = gs ^ (row & 7);
        gl_lds16(Bt + (size_t)(n0 + row) * K + kb + g * 8, &Bs[nxt][e * 8]);
      }
    }
    bf16x8 af[2][2], bfr[4][2];
    for (int mt = 0; mt < 2; mt++)
      for (int kc = 0; kc < 2; kc++) {
        int row = wm + mt * 16 + l15;
        int gs = (kc * 4 + quad) ^ (row & 7);
        af[mt][kc] = *(const bf16x8*)&As[cur][row * 64 + gs * 8];
      }
    for (int nt = 0; nt < 4; nt++)
      for (int kc = 0; kc < 2; kc++) {
        int row = wn + nt * 16 + l15;
        int gs = (kc * 4 + quad) ^ (row & 7);
        bfr[nt][kc] = *(const bf16x8*)&Bs[cur][row * 64 + gs * 8];
      }
    for (int mt = 0; mt < 2; mt++)
      for (int nt = 0; nt < 4; nt++)
        for (int kc = 0; kc < 2; kc++)
          acc[mt][nt] = mfma16(af[mt][kc], bfr[nt][kc], acc[mt][nt]);
  }
  for (int mt = 0; mt < 2; mt++)
    for (int nt = 0; nt < 4; nt++)
      for (int r = 0; r < 4; r++) {
        int row = m0 + wm + mt * 16 + quad * 4 + r;
        int col = n0 + wn + nt * 16 + l15;
        C[(size_t)row * N + col] = acc[mt][nt][r] + bias[col];
      }
}

// ---------------- flash attention (R5 config, pre-swizzled q/k) -------------
__global__ __launch_bounds__(256, 4)
void attn_kernel(const u16* __restrict__ q, const u16* __restrict__ k,
                 const u16* __restrict__ vt, const uint64_t* __restrict__ bitsT,
                 u16* __restrict__ out) {
  int blk = blockIdx.x;
  int qt = blk & 31;
  int bh = blk >> 5;
  int b = bh >> 4, h = bh & 15;
  int q0 = qt * 64;
  int t = threadIdx.x, lane = t & 63, w = t >> 6;
  int l15 = lane & 15, quad = lane >> 4;

  __shared__ __align__(16) u16 sQ[64 * 64];
  __shared__ __align__(16) u16 sK[2][64 * 64];
  __shared__ __align__(16) u16 sV[2][64 * 64];

  {
    int e0 = t, e1 = 256 + t;
    const u16* qim = q + ((size_t)bh * 32 + qt) * 4096;
    const u16* kim = k + (size_t)bh * 32 * 4096;
    gl_lds16(qim + e0 * 8, &sQ[e0 * 8]);
    gl_lds16(qim + e1 * 8, &sQ[e1 * 8]);
    gl_lds16(kim + e0 * 8, &sK[0][e0 * 8]);
    gl_lds16(kim + e1 * 8, &sK[0][e1 * 8]);
    int r0 = e0 >> 3, g0 = (e0 & 7) ^ (r0 & 7);
    int r1 = e1 >> 3, g1 = (e1 & 7) ^ (r1 & 7);
    gl_lds16(vt + ((size_t)bh * 64 + r0) * 2048 + g0 * 8, &sV[0][e0 * 8]);
    gl_lds16(vt + ((size_t)bh * 64 + r1) * 2048 + g1 * 8, &sV[0][e1 * 8]);
  }
  __syncthreads();

  bf16x8 bq[2];
  {
    int row = w * 16 + l15;
    for (int kc = 0; kc < 2; kc++) {
      int gs = (kc * 4 + quad) ^ (row & 7);
      bq[kc] = *(const bf16x8*)&sQ[row * 64 + gs * 8];
    }
  }

  const f32x4 zf = {0.f, 0.f, 0.f, 0.f};
  float l_i = 0.f;
  f32x4 acc_o[4];
  for (int dt = 0; dt < 4; dt++) acc_o[dt] = zf;
  const int qrow = q0 + w * 16 + l15;

  #pragma unroll 2
  for (int j64 = 0; j64 < 32; j64++) {
    if (j64) __syncthreads();
    int cur = j64 & 1;
    if (j64 + 1 < 32) {
      int nxt = cur ^ 1, j0n = (j64 + 1) * 64;
      int e0 = t, e1 = 256 + t;
      const u16* kim = k + ((size_t)bh * 32 + j64 + 1) * 4096;
      gl_lds16(kim + e0 * 8, &sK[nxt][e0 * 8]);
      gl_lds16(kim + e1 * 8, &sK[nxt][e1 * 8]);
      int r0 = e0 >> 3, g0 = (e0 & 7) ^ (r0 & 7);
      int r1 = e1 >> 3, g1 = (e1 & 7) ^ (r1 & 7);
      gl_lds16(vt + ((size_t)bh * 64 + r0) * 2048 + j0n + g0 * 8, &sV[nxt][e0 * 8]);
      gl_lds16(vt + ((size_t)bh * 64 + r1) * 2048 + j0n + g1 * 8, &sV[nxt][e1 * 8]);
    }
    const u16* sKc = sK[cur];
    const u16* sVc = sV[cur];

    uint64_t word = bitsT[((size_t)(b * 32 + j64)) * 2048 + qrow];
    uint64_t sh = word >> (quad * 4);
    uint32_t mlo = (uint32_t)sh, mhi = (uint32_t)(sh >> 32);

    float p[16];
    {
      f32x4 st[4];
      for (int jt = 0; jt < 4; jt++) {
        st[jt] = zf;
        int row = jt * 16 + l15;
        for (int kc = 0; kc < 2; kc++) {
          int gs = (kc * 4 + quad) ^ (row & 7);
          bf16x8 ak = *(const bf16x8*)&sKc[row * 64 + gs * 8];
          st[jt] = mfma16(ak, bq[kc], st[jt]);
        }
      }
      for (int jt = 0; jt < 4; jt++) {
        uint32_t mw = (jt & 2) ? mhi : mlo;
        int base = (jt & 1) * 16;
        for (int r = 0; r < 4; r++) {
          bool on = (mw >> (base + r)) & 1u;
          float e = exp2f(st[jt][r]);
          p[jt * 4 + r] = on ? e : 0.f;
        }
      }
    }
    float rsum = 0.f;
    for (int i = 0; i < 16; i++) rsum += p[i];
    rsum += __shfl_xor(rsum, 16);
    rsum += __shfl_xor(rsum, 32);
    l_i += rsum;

    for (int c = 0; c < 2; c++) {
      union { bf16x8 v; uint32_t d[4]; } bp;
      bp.d[0] = pk_trunc(p[(2 * c) * 4 + 0], p[(2 * c) * 4 + 1]);
      bp.d[1] = pk_trunc(p[(2 * c) * 4 + 2], p[(2 * c) * 4 + 3]);
      bp.d[2] = pk_trunc(p[(2 * c + 1) * 4 + 0], p[(2 * c + 1) * 4 + 1]);
      bp.d[3] = pk_trunc(p[(2 * c + 1) * 4 + 2], p[(2 * c + 1) * 4 + 3]);
      for (int dt = 0; dt < 4; dt++) {
        int drow = dt * 16 + l15;
        int gpos = (4 * c + quad) ^ (drow & 7);
        bf16x8 av = *(const bf16x8*)&sVc[drow * 64 + gpos * 8];
        acc_o[dt] = mfma16(av, bp.v, acc_o[dt]);
      }
    }
  }
  float rl = (l_i > 0.f) ? 1.0f / l_i : 0.f;
  size_t obase = ((size_t)b * 2048 + qrow) * 1024 + h * 64;
  for (int dt = 0; dt < 4; dt++) {
    ushort4 o;
    o.x = f2bf(acc_o[dt][0] * rl);
    o.y = f2bf(acc_o[dt][1] * rl);
    o.z = f2bf(acc_o[dt][2] * rl);
    o.w = f2bf(acc_o[dt][3] * rl);
    *(ushort4*)&out[obase + dt * 16 + quad * 4] = o;
  }
}

extern "C" void kernel_launch(void* const* d_in, const int* in_sizes, int n_in,
                              void* d_out, int out_size, void* d_ws, size_t ws_size,
                              hipStream_t stream) {
  const float* x = (const float*)d_in[0];
  const int* mask = (const int*)d_in[1];
  const float* gamma = (const float*)d_in[2];
  const float* beta = (const float*)d_in[3];
  const float* wqkv = (const float*)d_in[4];
  const float* wout = (const float*)d_in[5];
  const float* bout = (const float*)d_in[6];
  float* out = (float*)d_out;

  uint8_t* ws = (uint8_t*)d_ws;
  size_t o = 0;
  uint64_t* mbits = (uint64_t*)(ws + o); o += (size_t)TOK * 32 * 8;
  u16* wqkvT = (u16*)(ws + o); o += (size_t)3 * INNER_ * D_ * 2;
  u16* woutT = (u16*)(ws + o); o += (size_t)INNER_ * D_ * 2;
  u16* xn    = (u16*)(ws + o); o += (size_t)TOK * D_ * 2;
  u16* qb    = (u16*)(ws + o); o += (size_t)TOK * INNER_ * 2;
  u16* kb    = (u16*)(ws + o); o += (size_t)TOK * INNER_ * 2;
  u16* vtb   = (u16*)(ws + o); o += (size_t)TOK * INNER_ * 2;
  u16* ao    = (u16*)(ws + o); o += (size_t)TOK * INNER_ * 2;
  float2* rtab = (float2*)(ws + o); o += (size_t)2048 * 32 * 8;

  prep_kernel<<<13568, 256, 0, stream>>>(x, gamma, beta, xn, wqkv, wqkvT,
                                         wout, woutT, mask, mbits, rtab);
  gemm_qkv<<<dim3(3 * INNER_ / 128, TOK / 128), 256, 0, stream>>>(xn, wqkvT, rtab, qb, kb, vtb);
  attn_kernel<<<B_ * H_ * (N_ / 64), 256, 0, stream>>>(qb, kb, vtb, mbits, ao);
  gemm_out<<<dim3(D_ / 128, TOK / 64), 256, 0, stream>>>(ao, woutT, out, bout);
}

// Round 8
// 217.902 us; speedup vs baseline: 1.1475x; 1.0547x over previous
//
#include <hip/hip_runtime.h>
#include <stdint.h>
#include <math.h>

#define B_ 2
#define N_ 2048
#define D_ 1024
#define H_ 16
#define HD_ 64
#define TOK (B_*N_)        // 4096 tokens
#define INNER_ (H_*HD_)    // 1024

typedef unsigned short u16;
typedef __attribute__((ext_vector_type(8))) short bf16x8;
typedef __attribute__((ext_vector_type(4))) float f32x4;

__device__ __forceinline__ float bf2f(u16 u) {
  union { uint32_t i; float f; } v; v.i = ((uint32_t)u) << 16; return v.f;
}
__device__ __forceinline__ u16 f2bf(float f) {
  union { uint32_t i; float f; } v; v.f = f;
  uint32_t r = ((v.i >> 16) & 1u) + 0x7fffu;   // round-to-nearest-even
  return (u16)((v.i + r) >> 16);
}
__device__ __forceinline__ uint32_t pk_trunc(float a, float b) {
  return __builtin_amdgcn_perm(__float_as_uint(b), __float_as_uint(a), 0x07060302);
}
__device__ __forceinline__ uint32_t pk_rnd(float a, float b) {
  uint32_t ua = __float_as_uint(a) + 0x8000u;
  uint32_t ub = __float_as_uint(b) + 0x8000u;
  return __builtin_amdgcn_perm(ub, ua, 0x07060302);
}
__device__ __forceinline__ void gl_lds16(const void* g, void* l) {
  __builtin_amdgcn_global_load_lds(
      (const __attribute__((address_space(1))) uint32_t*)g,
      (__attribute__((address_space(3))) uint32_t*)l, 16, 0, 0);
}
__device__ __forceinline__ f32x4 mfma16(bf16x8 a, bf16x8 b, f32x4 c) {
  return __builtin_amdgcn_mfma_f32_16x16x32_bf16(a, b, c, 0, 0, 0);
}

// ---------------- fused prologue: ln / transposes / pack_mask / rtab --------
// block ranges: [0,4096) ln | [4096,4864) T(wqkv) | [4864,5120) T(wout)
//               | [5120,13312) pack_mask | [13312,13568) rtab
__global__ void prep_kernel(const float* __restrict__ x, const float* __restrict__ gamma,
                            const float* __restrict__ beta, u16* __restrict__ xn,
                            const float* __restrict__ wqkv, u16* __restrict__ wqkvT,
                            const float* __restrict__ wout, u16* __restrict__ woutT,
                            const int* __restrict__ mask, uint64_t* __restrict__ bits,
                            float2* __restrict__ rtab) {
  __shared__ u16 tile[64][65];
  __shared__ float red[8];
  int blk = blockIdx.x, t = threadIdx.x;
  if (blk < 4096) {                       // ----- LayerNorm row -----
    int row = blk;
    const float* xr = x + (size_t)row * D_;
    float4 u = *(const float4*)(xr + t * 4);
    float s = u.x + u.y + u.z + u.w;
    float ss = u.x * u.x + u.y * u.y + u.z * u.z + u.w * u.w;
    for (int off = 1; off < 64; off <<= 1) {
      s += __shfl_xor(s, off);
      ss += __shfl_xor(ss, off);
    }
    int wid = t >> 6, lane = t & 63;
    if (lane == 0) { red[wid] = s; red[wid + 4] = ss; }
    __syncthreads();
    s = red[0] + red[1] + red[2] + red[3];
    ss = red[4] + red[5] + red[6] + red[7];
    float mu = s * (1.0f / D_);
    float var = ss * (1.0f / D_) - mu * mu;
    float rinv = rsqrtf(var + 1e-5f);
    float4 g4 = *(const float4*)(gamma + t * 4);
    float4 b4 = *(const float4*)(beta + t * 4);
    ushort4 o;
    o.x = f2bf((u.x - mu) * rinv * g4.x + b4.x);
    o.y = f2bf((u.y - mu) * rinv * g4.y + b4.y);
    o.z = f2bf((u.z - mu) * rinv * g4.z + b4.z);
    o.w = f2bf((u.w - mu) * rinv * g4.w + b4.w);
    *(ushort4*)(xn + (size_t)row * D_ + t * 4) = o;
  } else if (blk < 5120) {                // ----- weight transpose fp32->bf16 -----
    const float* in; u16* outp; int R, C, bx, by;
    if (blk < 4864) { int idx = blk - 4096; in = wqkv; outp = wqkvT; R = 1024; C = 3072; bx = idx % 48; by = idx / 48; }
    else            { int idx = blk - 4864; in = wout; outp = woutT; R = 1024; C = 1024; bx = idx % 16; by = idx / 16; }
    int c0 = bx * 64, r0 = by * 64;
    int c = t & 63, r4 = t >> 6;
    for (int i = 0; i < 16; i++) {
      int r = r4 + i * 4;
      tile[c][r] = f2bf(in[(size_t)(r0 + r) * C + c0 + c]);
    }
    __syncthreads();
    int rr = t & 63, cc4 = t >> 6;
    for (int i = 0; i < 16; i++) {
      int cc = cc4 + i * 4;
      outp[(size_t)(c0 + cc) * R + r0 + rr] = tile[cc][rr];
    }
  } else if (blk < 13312) {               // ----- mask -> bitsT[b][j64][row] -----
    int idx = blk - 5120;
    int lane = t & 63, w = t >> 6;
    int seg = idx * 4 + w;
    int row = seg >> 3, s = seg & 7;
    const int* mp = mask + (size_t)row * 2048 + s * 256;
    int b = row >> 11, i = row & 2047;
    uint64_t* bp = bits + (size_t)b * 32 * 2048 + i;
    for (int j = 0; j < 4; j++) {
      int m = mp[j * 64 + lane];
      uint64_t bm = __ballot(m > 0);
      if (lane == 0) bp[(size_t)(s * 4 + j) * 2048] = bm;
    }
  } else {                                 // ----- RoPE sin/cos table -----
    int i = (blk - 13312) * 256 + t;
    int pos = i >> 5, p = i & 31;
    float inv = exp2f(-(float)p * (13.287712379549449f / 32.0f));
    float sn, cs;
    sincosf((float)pos * inv, &sn, &cs);
    rtab[i] = make_float2(sn, cs);
  }
}

// ------- QKV GEMM + fused RoPE/head-reorder epilogue -----------------------
// q/k written PRE-SWIZZLED in attn's LDS image order, per (bh, 64-token tile):
//   image[e*8 + o] = value(row = e>>3, dim = ((e&7)^(row&7))*8 + o)
// -> attn staging is a flat contiguous 4096-u16 copy.  V written row-major
// [bh][d][2048] with within-64 slot perm: j=32c+16hi+4q+r -> 32c+8q+4hi+r.
__global__ void gemm_qkv(const u16* __restrict__ A, const u16* __restrict__ Bt,
                         const float2* __restrict__ rtab,
                         u16* __restrict__ q, u16* __restrict__ k,
                         u16* __restrict__ vt) {
  const int K = 1024;
  __shared__ __align__(16) u16 smem[16384];   // As=smem[0:8192], Bs=smem[8192:]
  u16* As = smem;
  u16* Bs = smem + 8192;
  const int t = threadIdx.x;
  const int lane = t & 63, wid = t >> 6;
  const int m0 = blockIdx.y * 128, n0 = blockIdx.x * 128;
  const int wm = (wid >> 1) * 64, wn = (wid & 1) * 64;
  const int l15 = lane & 15, quad = lane >> 4;

  f32x4 acc[4][4];
  const f32x4 zf = {0.f, 0.f, 0.f, 0.f};
  for (int i = 0; i < 4; i++) for (int j = 0; j < 4; j++) acc[i][j] = zf;

  for (int kb = 0; kb < K; kb += 64) {
    for (int i = 0; i < 4; i++) {
      int e = i * 256 + t;
      int row = e >> 3, gs = e & 7;
      int g = gs ^ (row & 7);
      gl_lds16(A + (size_t)(m0 + row) * K + kb + g * 8, &As[e * 8]);
      gl_lds16(Bt + (size_t)(n0 + row) * K + kb + g * 8, &Bs[e * 8]);
    }
    __syncthreads();
    bf16x8 af[4][2], bfr[4][2];
    for (int mt = 0; mt < 4; mt++)
      for (int kc = 0; kc < 2; kc++) {
        int row = wm + mt * 16 + l15;
        int gs = (kc * 4 + quad) ^ (row & 7);
        af[mt][kc] = *(const bf16x8*)&As[row * 64 + gs * 8];
      }
    for (int nt = 0; nt < 4; nt++)
      for (int kc = 0; kc < 2; kc++) {
        int row = wn + nt * 16 + l15;
        int gs = (kc * 4 + quad) ^ (row & 7);
        bfr[nt][kc] = *(const bf16x8*)&Bs[row * 64 + gs * 8];
      }
    for (int mt = 0; mt < 4; mt++)
      for (int nt = 0; nt < 4; nt++)
        for (int kc = 0; kc < 2; kc++)
          acc[mt][nt] = mfma16(af[mt][kc], bfr[nt][kc], acc[mt][nt]);
    __syncthreads();
  }

  const int sec = n0 >> 10;                       // 0=q 1=k 2=v
  const int h_base = (n0 & 1023) >> 6;
  if (sec < 2) {
    // RoPE into LDS images (wave-private 4096-u16 region), then coalesced out
    u16* dst = sec ? k : q;
    const float scale = sec ? 1.0f : 0.125f * 1.4426950408889634f;
    const int img = (wn >> 6) * 2 + (wm >> 6);     // wave-uniform
    u16* im = smem + img * 4096;
    for (int mt = 0; mt < 4; mt++)
      for (int r = 0; r < 4; r++) {
        int lr = mt * 16 + quad * 4 + r;           // local row 0..63
        int rowg = m0 + wm + lr;
        int pos = rowg & 2047;
        float2 c0 = rtab[pos * 32 + l15];
        float2 c1 = rtab[pos * 32 + 16 + l15];
        float a0 = acc[mt][0][r], a1 = acc[mt][1][r];
        float a2 = acc[mt][2][r], a3 = acc[mt][3][r];
        float o0 = (a0 * c0.y - a2 * c0.x) * scale;   // d = l15
        float o1 = (a1 * c1.y - a3 * c1.x) * scale;   // d = l15+16
        float o2 = (a2 * c0.y + a0 * c0.x) * scale;   // d = l15+32
        float o3 = (a3 * c1.y + a1 * c1.x) * scale;   // d = l15+48
        int rx = lr & 7, dl = l15 & 7, dh = l15 >> 3;
        int base = lr * 64;
        im[base + ((0 + dh) ^ rx) * 8 + dl] = f2bf(o0);
        im[base + ((2 + dh) ^ rx) * 8 + dl] = f2bf(o1);
        im[base + ((4 + dh) ^ rx) * 8 + dl] = f2bf(o2);
        im[base + ((6 + dh) ^ rx) * 8 + dl] = f2bf(o3);
      }
    __syncthreads();
    for (int i = 0; i < 8; i++) {
      int u = i * 2048 + t * 8;
      int ig = u >> 12, off = u & 4095;
      int hh = ig >> 1, tt = ig & 1;
      int rowg0 = m0 + tt * 64;
      int bb = rowg0 >> 11;
      int tl = (rowg0 & 2047) >> 6;
      size_t base = ((size_t)(bb * 16 + h_base + hh) * 32 + tl) * 4096 + off;
      *(uint4*)&dst[base] = *(const uint4*)&smem[u];
    }
  } else {
    // vt[bh][d][2048], slot perm within each 64-token block
    const int h = h_base + (wn >> 6);
    for (int mt = 0; mt < 4; mt++) {
      int tb = wm + mt * 16;
      int bb = (m0 + tb) >> 11;
      int n64 = ((m0 + tb) & 2047) & ~63;
      int slot = n64 + (tb & 32) + ((tb & 16) >> 2) + quad * 8;
      for (int nt = 0; nt < 4; nt++) {
        int d = nt * 16 + l15;
        size_t base = ((size_t)(bb * 16 + h) * 64 + d) * 2048 + slot;
        uint2 o;
        o.x = pk_rnd(acc[mt][nt][0], acc[mt][nt][1]);
        o.y = pk_rnd(acc[mt][nt][2], acc[mt][nt][3]);
        *(uint2*)&vt[base] = o;
      }
    }
  }
}

// ------- out-proj GEMM, 64x128 tile, double-buffered -----------------------
__global__ void gemm_out(const u16* __restrict__ A, const u16* __restrict__ Bt,
                         float* __restrict__ C, const float* __restrict__ bias) {
  const int N = 1024, K = 1024;
  __shared__ __align__(16) u16 As[2][64 * 64];
  __shared__ __align__(16) u16 Bs[2][128 * 64];
  const int t = threadIdx.x;
  const int lane = t & 63, wid = t >> 6;
  const int m0 = blockIdx.y * 64, n0 = blockIdx.x * 128;
  const int wm = (wid >> 1) * 32, wn = (wid & 1) * 64;
  const int l15 = lane & 15, quad = lane >> 4;

  f32x4 acc[2][4];
  const f32x4 zf = {0.f, 0.f, 0.f, 0.f};
  for (int i = 0; i < 2; i++) for (int j = 0; j < 4; j++) acc[i][j] = zf;

  {
    for (int i = 0; i < 2; i++) {
      int e = i * 256 + t;
      int row = e >> 3, gs = e & 7, g = gs ^ (row & 7);
      gl_lds16(A + (size_t)(m0 + row) * K + g * 8, &As[0][e * 8]);
    }
    for (int i = 0; i < 4; i++) {
      int e = i * 256 + t;
      int row = e >> 3, gs = e & 7, g = gs ^ (row & 7);
      gl_lds16(Bt + (size_t)(n0 + row) * K + g * 8, &Bs[0][e * 8]);
    }
  }
  for (int ki = 0; ki < 16; ki++) {
    int cur = ki & 1;
    __syncthreads();
    if (ki + 1 < 16) {
      int nxt = cur ^ 1, kb = (ki + 1) * 64;
      for (int i = 0; i < 2; i++) {
        int e = i * 256 + t;
        int row = e >> 3, gs = e & 7, g = gs ^ (row & 7);
        gl_lds16(A + (size_t)(m0 + row) * K + kb + g * 8, &As[nxt][e * 8]);
      }
      for (int i = 0; i < 4; i++) {
        int e = i * 256 + t;
        int row = e >> 3, gs = e & 7, g = gs ^ (row & 7);
        gl_lds16(Bt + (size_t)(n0 + row) * K + kb + g * 8, &Bs[nxt][e * 8]);
      }
    }
    bf16x8 af[2][2], bfr[4][2];
    for (int mt = 0; mt < 2; mt++)
      for (int kc = 0; kc < 2; kc++) {
        int row = wm + mt * 16 + l15;
        int gs = (kc * 4 + quad) ^ (row & 7);
        af[mt][kc] = *(const bf16x8*)&As[cur][row * 64 + gs * 8];
      }
    for (int nt = 0; nt < 4; nt++)
      for (int kc = 0; kc < 2; kc++) {
        int row = wn + nt * 16 + l15;
        int gs = (kc * 4 + quad) ^ (row & 7);
        bfr[nt][kc] = *(const bf16x8*)&Bs[cur][row * 64 + gs * 8];
      }
    for (int mt = 0; mt < 2; mt++)
      for (int nt = 0; nt < 4; nt++)
        for (int kc = 0; kc < 2; kc++)
          acc[mt][nt] = mfma16(af[mt][kc], bfr[nt][kc], acc[mt][nt]);
  }
  for (int mt = 0; mt < 2; mt++)
    for (int nt = 0; nt < 4; nt++)
      for (int r = 0; r < 4; r++) {
        int row = m0 + wm + mt * 16 + quad * 4 + r;
        int col = n0 + wn + nt * 16 + l15;
        C[(size_t)row * N + col] = acc[mt][nt][r] + bias[col];
      }
}

// ---------------- flash attention (pre-swizzled q/k) ------------------------
// S^T = K.Q^T per 16x16 tile; fixed-base softmax (scores bounded, m=0 exact);
// raw v_exp_f32 via builtin; row-sum via ones-A-fragment MFMA on the SAME
// truncated-P B-fragment used for PV (denominator consistent with numerator).
__global__ __launch_bounds__(256, 4)
void attn_kernel(const u16* __restrict__ q, const u16* __restrict__ k,
                 const u16* __restrict__ vt, const uint64_t* __restrict__ bitsT,
                 u16* __restrict__ out) {
  int blk = blockIdx.x;
  int qt = blk & 31;
  int bh = blk >> 5;
  int b = bh >> 4, h = bh & 15;
  int t = threadIdx.x, lane = t & 63, w = t >> 6;
  int l15 = lane & 15, quad = lane >> 4;

  __shared__ __align__(16) u16 sQ[64 * 64];
  __shared__ __align__(16) u16 sK[2][64 * 64];
  __shared__ __align__(16) u16 sV[2][64 * 64];

  {
    int e0 = t, e1 = 256 + t;
    const u16* qim = q + ((size_t)bh * 32 + qt) * 4096;
    const u16* kim = k + (size_t)bh * 32 * 4096;
    gl_lds16(qim + e0 * 8, &sQ[e0 * 8]);
    gl_lds16(qim + e1 * 8, &sQ[e1 * 8]);
    gl_lds16(kim + e0 * 8, &sK[0][e0 * 8]);
    gl_lds16(kim + e1 * 8, &sK[0][e1 * 8]);
    int r0 = e0 >> 3, g0 = (e0 & 7) ^ (r0 & 7);
    int r1 = e1 >> 3, g1 = (e1 & 7) ^ (r1 & 7);
    gl_lds16(vt + ((size_t)bh * 64 + r0) * 2048 + g0 * 8, &sV[0][e0 * 8]);
    gl_lds16(vt + ((size_t)bh * 64 + r1) * 2048 + g1 * 8, &sV[0][e1 * 8]);
  }
  __syncthreads();

  bf16x8 bq[2];
  {
    int row = w * 16 + l15;
    for (int kc = 0; kc < 2; kc++) {
      int gs = (kc * 4 + quad) ^ (row & 7);
      bq[kc] = *(const bf16x8*)&sQ[row * 64 + gs * 8];
    }
  }
  // ones A-fragment: A[m][k] = (m==0) -> C row 0 = column sums of B
  bf16x8 aone;
  {
    union { bf16x8 v8; uint32_t d[4]; } uo;
    uint32_t val = (l15 == 0) ? 0x3F803F80u : 0u;
    uo.d[0] = val; uo.d[1] = val; uo.d[2] = val; uo.d[3] = val;
    aone = uo.v8;
  }

  const f32x4 zf = {0.f, 0.f, 0.f, 0.f};
  f32x4 acc_l = zf;
  f32x4 acc_o[4];
  for (int dt = 0; dt < 4; dt++) acc_o[dt] = zf;
  const int qrow = qt * 64 + w * 16 + l15;

  #pragma unroll 2
  for (int j64 = 0; j64 < 32; j64++) {
    if (j64) __syncthreads();
    int cur = j64 & 1;
    if (j64 + 1 < 32) {
      int nxt = cur ^ 1, j0n = (j64 + 1) * 64;
      int e0 = t, e1 = 256 + t;
      const u16* kim = k + ((size_t)bh * 32 + j64 + 1) * 4096;
      gl_lds16(kim + e0 * 8, &sK[nxt][e0 * 8]);
      gl_lds16(kim + e1 * 8, &sK[nxt][e1 * 8]);
      int r0 = e0 >> 3, g0 = (e0 & 7) ^ (r0 & 7);
      int r1 = e1 >> 3, g1 = (e1 & 7) ^ (r1 & 7);
      gl_lds16(vt + ((size_t)bh * 64 + r0) * 2048 + j0n + g0 * 8, &sV[nxt][e0 * 8]);
      gl_lds16(vt + ((size_t)bh * 64 + r1) * 2048 + j0n + g1 * 8, &sV[nxt][e1 * 8]);
    }
    const u16* sKc = sK[cur];
    const u16* sVc = sV[cur];

    uint64_t word = bitsT[((size_t)(b * 32 + j64)) * 2048 + qrow];
    uint64_t sh = word >> (quad * 4);
    uint32_t mlo = (uint32_t)sh, mhi = (uint32_t)(sh >> 32);

    float p[16];
    {
      f32x4 st[4];
      for (int jt = 0; jt < 4; jt++) {
        st[jt] = zf;
        int row = jt * 16 + l15;
        for (int kc = 0; kc < 2; kc++) {
          int gs = (kc * 4 + quad) ^ (row & 7);
          bf16x8 ak = *(const bf16x8*)&sKc[row * 64 + gs * 8];
          st[jt] = mfma16(ak, bq[kc], st[jt]);
        }
      }
      for (int jt = 0; jt < 4; jt++) {
        uint32_t mw = (jt & 2) ? mhi : mlo;
        int base = (jt & 1) * 16;
        for (int r = 0; r < 4; r++) {
          bool on = (mw >> (base + r)) & 1u;
          float e = __builtin_amdgcn_exp2f(st[jt][r]);  // raw v_exp_f32
          p[jt * 4 + r] = on ? e : 0.f;
        }
      }
    }

    for (int c = 0; c < 2; c++) {
      union { bf16x8 v; uint32_t d[4]; } bp;
      bp.d[0] = pk_trunc(p[(2 * c) * 4 + 0], p[(2 * c) * 4 + 1]);
      bp.d[1] = pk_trunc(p[(2 * c) * 4 + 2], p[(2 * c) * 4 + 3]);
      bp.d[2] = pk_trunc(p[(2 * c + 1) * 4 + 0], p[(2 * c + 1) * 4 + 1]);
      bp.d[3] = pk_trunc(p[(2 * c + 1) * 4 + 2], p[(2 * c + 1) * 4 + 3]);
      acc_l = mfma16(aone, bp.v, acc_l);     // denominator on MFMA pipe
      for (int dt = 0; dt < 4; dt++) {
        int drow = dt * 16 + l15;
        int gpos = (4 * c + quad) ^ (drow & 7);
        bf16x8 av = *(const bf16x8*)&sVc[drow * 64 + gpos * 8];
        acc_o[dt] = mfma16(av, bp.v, acc_o[dt]);
      }
    }
  }
  // l for q-row (w*16+l15) lives in lane (quad0, l15), reg 0 — broadcast
  float lsum = __shfl(acc_l[0], l15);
  float rl = (lsum > 0.f) ? __builtin_amdgcn_rcpf(lsum) : 0.f;
  size_t obase = ((size_t)b * 2048 + qrow) * 1024 + h * 64;
  for (int dt = 0; dt < 4; dt++) {
    ushort4 o;
    o.x = f2bf(acc_o[dt][0] * rl);
    o.y = f2bf(acc_o[dt][1] * rl);
    o.z = f2bf(acc_o[dt][2] * rl);
    o.w = f2bf(acc_o[dt][3] * rl);
    *(ushort4*)&out[obase + dt * 16 + quad * 4] = o;
  }
}

extern "C" void kernel_launch(void* const* d_in, const int* in_sizes, int n_in,
                              void* d_out, int out_size, void* d_ws, size_t ws_size,
                              hipStream_t stream) {
  const float* x = (const float*)d_in[0];
  const int* mask = (const int*)d_in[1];
  const float* gamma = (const float*)d_in[2];
  const float* beta = (const float*)d_in[3];
  const float* wqkv = (const float*)d_in[4];
  const float* wout = (const float*)d_in[5];
  const float* bout = (const float*)d_in[6];
  float* out = (float*)d_out;

  uint8_t* ws = (uint8_t*)d_ws;
  size_t o = 0;
  uint64_t* mbits = (uint64_t*)(ws + o); o += (size_t)TOK * 32 * 8;
  u16* wqkvT = (u16*)(ws + o); o += (size_t)3 * INNER_ * D_ * 2;
  u16* woutT = (u16*)(ws + o); o += (size_t)INNER_ * D_ * 2;
  u16* xn    = (u16*)(ws + o); o += (size_t)TOK * D_ * 2;
  u16* qb    = (u16*)(ws + o); o += (size_t)TOK * INNER_ * 2;
  u16* kb    = (u16*)(ws + o); o += (size_t)TOK * INNER_ * 2;
  u16* vtb   = (u16*)(ws + o); o += (size_t)TOK * INNER_ * 2;
  u16* ao    = (u16*)(ws + o); o += (size_t)TOK * INNER_ * 2;
  float2* rtab = (float2*)(ws + o); o += (size_t)2048 * 32 * 8;

  prep_kernel<<<13568, 256, 0, stream>>>(x, gamma, beta, xn, wqkv, wqkvT,
                                         wout, woutT, mask, mbits, rtab);
  gemm_qkv<<<dim3(3 * INNER_ / 128, TOK / 128), 256, 0, stream>>>(xn, wqkvT, rtab, qb, kb, vtb);
  attn_kernel<<<B_ * H_ * (N_ / 64), 256, 0, stream>>>(qb, kb, vtb, mbits, ao);
  gemm_out<<<dim3(D_ / 128, TOK / 64), 256, 0, stream>>>(ao, woutT, out, bout);
}